// Round 16
// baseline (2415.734 us; speedup 1.0000x reference)
//
#include <hip/hip_runtime.h>
#include <hip/hip_bf16.h>
#include <math.h>

// ---------------------------------------------------------------------------
// EEGMamba forward. Round 25: R24 NaN root-caused — Y1 = G@Xt^T contracts
// K = s over [0,64) but Xt cols s>=lchunk were uninitialized LDS; the
// matching G entries are exact zeros, but MFMA 0*NaN = NaN into VALID
// outputs. Fix: zero exactly Xt cols [lchunk,64) (disjoint from staging
// writes -> no extra barrier). All other R24 improvements kept: coalesced
// block-coop Xt staging, Sn as reg-converted global B-fragments, packed
// 76.9KB LDS (2 blocks/CU). Pass 1 = state12 MFMA. Base = R23 (2289 us).
#define D_MODEL   200
#define N_LAYER   12
#define NHEADS    8
#define HEADDIM   50
#define D_STATE   64
#define D_INNER   400
#define CONV_DIM  528
#define D_IN_PROJ 936
#define D_CONV    4
#define EPS       1e-5f

#define BATCH 16
#define CH    19
#define LLEN  30
#define SEQ   570
#define NTOK  9120
#define NFREQ 101

typedef __attribute__((ext_vector_type(8))) short s8v;
typedef __attribute__((ext_vector_type(4))) float f32x4;

__device__ __forceinline__ short f2bf(float f) {
    unsigned u = __float_as_uint(f);
    u += 0x7FFFu + ((u >> 16) & 1u);      // RNE
    return (short)(u >> 16);
}

// ---------------------------------------------------------------------------
// bf16 MFMA GEMM: C[M,N] = rowscale[m] * (A[M,Kp] @ W[N,Kp]^T) (+bias) (+C)
__global__ __launch_bounds__(256) void gemm_bf16(
    const short* __restrict__ A, const short* __restrict__ W,
    const float* __restrict__ bias, const float* __restrict__ rowscale,
    float* __restrict__ C, int M, int N, int Kp, int accum)
{
    __shared__ __align__(16) short As[128][40];
    __shared__ __align__(16) short Ws[128][40];

    int bm = blockIdx.y * 128;
    int bn = blockIdx.x * 128;
    int tid = threadIdx.x;
    int lane = tid & 63;
    int wv = tid >> 6;
    int wm = wv & 1, wn = wv >> 1;
    int lm = lane & 15, lg = lane >> 4;

    int sr = tid >> 1;
    int sh_ = (tid & 1) * 16;

    f32x4 acc[4][4];
#pragma unroll
    for (int i = 0; i < 4; i++)
#pragma unroll
        for (int j = 0; j < 4; j++) acc[i][j] = (f32x4)0.f;

    for (int k0 = 0; k0 < Kp; k0 += 32) {
        {
            s8v v0 = (s8v)0, v1 = (s8v)0;
            if (bm + sr < M) {
                const short* ga = A + (size_t)(bm + sr) * Kp + k0 + sh_;
                v0 = *(const s8v*)ga;
                v1 = *(const s8v*)(ga + 8);
            }
            *(s8v*)&As[sr][sh_] = v0;
            *(s8v*)&As[sr][sh_ + 8] = v1;
        }
        {
            s8v v0 = (s8v)0, v1 = (s8v)0;
            if (bn + sr < N) {
                const short* gw = W + (size_t)(bn + sr) * Kp + k0 + sh_;
                v0 = *(const s8v*)gw;
                v1 = *(const s8v*)(gw + 8);
            }
            *(s8v*)&Ws[sr][sh_] = v0;
            *(s8v*)&Ws[sr][sh_ + 8] = v1;
        }
        __syncthreads();

        s8v af[4], bf[4];
#pragma unroll
        for (int i = 0; i < 4; i++)
            af[i] = *(const s8v*)&As[wm * 64 + i * 16 + lm][lg * 8];
#pragma unroll
        for (int j = 0; j < 4; j++)
            bf[j] = *(const s8v*)&Ws[wn * 64 + j * 16 + lm][lg * 8];
#pragma unroll
        for (int i = 0; i < 4; i++)
#pragma unroll
            for (int j = 0; j < 4; j++)
                acc[i][j] = __builtin_amdgcn_mfma_f32_16x16x32_bf16(
                    af[i], bf[j], acc[i][j], 0, 0, 0);
        __syncthreads();
    }

#pragma unroll
    for (int j = 0; j < 4; j++) {
        int n = bn + wn * 64 + j * 16 + lm;
        if (n >= N) continue;
        float bv = bias ? bias[n] : 0.f;
#pragma unroll
        for (int i = 0; i < 4; i++) {
            int mbase = bm + wm * 64 + i * 16 + lg * 4;
#pragma unroll
            for (int r = 0; r < 4; r++) {
                int m = mbase + r;
                if (m >= M) continue;
                size_t idx = (size_t)m * N + n;
                float v = acc[i][j][r];
                if (rowscale) v *= rowscale[m];
                v += bv;
                if (accum) v += C[idx];
                C[idx] = v;
            }
        }
    }
}

// ---------------------------------------------------------------------------
// fp32 GEMM (fallback path)
__global__ __launch_bounds__(256) void gemm_nt(
    const float* __restrict__ A, const float* __restrict__ W,
    const float* __restrict__ bias, float* __restrict__ C,
    int M, int N, int K, int accum)
{
    const int BM = 128, BK = 16;
    __shared__ float As[16][BM + 4];
    __shared__ float Ws[16][BM + 4];

    int bm = blockIdx.y * BM;
    int bn = blockIdx.x * BM;
    int tid = threadIdx.x;
    int lr = tid >> 1;
    int lc = (tid & 1) * 8;
    int tx = tid & 15;
    int ty = tid >> 4;

    float acc[8][8];
#pragma unroll
    for (int i = 0; i < 8; i++)
#pragma unroll
        for (int j = 0; j < 8; j++) acc[i][j] = 0.f;

    for (int k0 = 0; k0 < K; k0 += BK) {
#pragma unroll
        for (int i = 0; i < 8; i++) {
            int gr = bm + lr, gk = k0 + lc + i;
            As[lc + i][lr] = (gr < M && gk < K) ? A[(size_t)gr * K + gk] : 0.f;
        }
#pragma unroll
        for (int i = 0; i < 8; i++) {
            int gr = bn + lr, gk = k0 + lc + i;
            Ws[lc + i][lr] = (gr < N && gk < K) ? W[(size_t)gr * K + gk] : 0.f;
        }
        __syncthreads();
#pragma unroll
        for (int kk = 0; kk < BK; kk++) {
            float a[8], bv[8];
#pragma unroll
            for (int i = 0; i < 8; i++) a[i] = As[kk][ty * 8 + i];
#pragma unroll
            for (int j = 0; j < 8; j++) bv[j] = Ws[kk][tx * 8 + j];
#pragma unroll
            for (int i = 0; i < 8; i++)
#pragma unroll
                for (int j = 0; j < 8; j++)
                    acc[i][j] = fmaf(a[i], bv[j], acc[i][j]);
        }
        __syncthreads();
    }

#pragma unroll
    for (int i = 0; i < 8; i++) {
        int gm = bm + ty * 8 + i;
        if (gm >= M) continue;
#pragma unroll
        for (int j = 0; j < 8; j++) {
            int gn = bn + tx * 8 + j;
            if (gn >= N) continue;
            float v = acc[i][j];
            if (bias) v += bias[gn];
            if (accum) v += C[(size_t)gm * N + gn];
            C[(size_t)gm * N + gn] = v;
        }
    }
}

// ---------------------------------------------------------------------------
__global__ __launch_bounds__(256) void cast_pad_kernel(
    const float* __restrict__ src, short* __restrict__ dst,
    int R, int K, int Kp)
{
    int idx = blockIdx.x * 256 + threadIdx.x;
    if (idx >= R * Kp) return;
    int r = idx / Kp, k = idx - r * Kp;
    dst[idx] = (k < K) ? f2bf(src[(size_t)r * K + k]) : (short)0;
}

// ---------------------------------------------------------------------------
__global__ __launch_bounds__(256) void time_conv_kernel(
    const float* __restrict__ x, const float* __restrict__ pw,
    float* __restrict__ traw)
{
    int br = blockIdx.x;
    __shared__ float xr[200];
    if (threadIdx.x < 200) xr[threadIdx.x] = x[(size_t)br * 200 + threadIdx.x];
    __syncthreads();
    if (threadIdx.x < 200) {
        int oc = threadIdx.x >> 3, j = threadIdx.x & 7;
        int start = j * 25 - 24;
        float acc = 0.f;
#pragma unroll
        for (int k = 0; k < 49; k++) {
            int d = start + k;
            if (d >= 0 && d < 200) acc = fmaf(xr[d], pw[oc * 49 + k], acc);
        }
        int b = br / SEQ, row = br % SEQ;
        traw[(((size_t)b * 25 + oc) * SEQ + row) * 8 + j] = acc;
    }
}

__global__ __launch_bounds__(256) void gn_stats_kernel(
    const float* __restrict__ traw, float* __restrict__ stats)
{
    int bg = blockIdx.x;
    int b = bg / 5, g = bg % 5;
    const float* base = traw + ((size_t)b * 25 + g * 5) * SEQ * 8;
    float s = 0.f, q = 0.f;
    for (int i = threadIdx.x; i < 5 * SEQ * 8; i += 256) {
        float v = base[i];
        s += v; q = fmaf(v, v, q);
    }
    __shared__ float rs[4], rq[4];
    int lane = threadIdx.x & 63, w = threadIdx.x >> 6;
#pragma unroll
    for (int o = 32; o; o >>= 1) { s += __shfl_xor(s, o, 64); q += __shfl_xor(q, o, 64); }
    if (lane == 0) { rs[w] = s; rq[w] = q; }
    __syncthreads();
    if (threadIdx.x == 0) {
        float S = rs[0] + rs[1] + rs[2] + rs[3];
        float Q = rq[0] + rq[1] + rq[2] + rq[3];
        float inv = 1.f / (5.f * SEQ * 8.f);
        float mean = S * inv;
        float var = Q * inv - mean * mean;
        stats[bg * 2] = mean;
        stats[bg * 2 + 1] = rsqrtf(var + EPS);
    }
}

__global__ __launch_bounds__(256) void gn_gelu_kernel(
    const float* __restrict__ traw, const float* __restrict__ stats,
    const float* __restrict__ gn_g, const float* __restrict__ gn_b,
    float* __restrict__ patch)
{
    int idx = blockIdx.x * 256 + threadIdx.x;
    if (idx >= NTOK * 200) return;
    int d = idx % 200;
    int row = (idx / 200) % SEQ;
    int b = idx / (200 * SEQ);
    int oc = d >> 3, j = d & 7;
    float v = traw[(((size_t)b * 25 + oc) * SEQ + row) * 8 + j];
    int g = oc / 5;
    float mean = stats[(b * 5 + g) * 2];
    float rstd = stats[(b * 5 + g) * 2 + 1];
    v = (v - mean) * rstd * gn_g[oc] + gn_b[oc];
    float ge = 0.5f * v * (1.f + erff(v * 0.70710678118654752f));
    patch[idx] = ge;
}

__global__ __launch_bounds__(256) void dft_init_kernel(float* __restrict__ CS)
{
    int idx = blockIdx.x * 256 + threadIdx.x;
    if (idx >= 202 * 200) return;
    int f = idx / 200, d = idx % 200;
    int fr = (f < NFREQ) ? f : (f - NFREQ);
    int m = (fr * d) % 200;
    float ang = -6.283185307179586f * (float)m * (1.f / 200.f);
    CS[idx] = (f < NFREQ) ? cosf(ang) : sinf(ang);
}

__global__ __launch_bounds__(256) void dft_init_bf_kernel(short* __restrict__ CS)
{
    int idx = blockIdx.x * 256 + threadIdx.x;
    if (idx >= 202 * 224) return;
    int f = idx / 224, d = idx - f * 224;
    short out = 0;
    if (d < 200) {
        int fr = (f < NFREQ) ? f : (f - NFREQ);
        int m = (fr * d) % 200;
        float ang = -6.283185307179586f * (float)m * (1.f / 200.f);
        out = f2bf((f < NFREQ) ? cosf(ang) : sinf(ang));
    }
    CS[idx] = out;
}

__global__ __launch_bounds__(256) void mag_kernel(
    const float* __restrict__ cs_out, float* __restrict__ magv)
{
    int idx = blockIdx.x * 256 + threadIdx.x;
    if (idx >= NTOK * NFREQ) return;
    int m = idx / NFREQ, f = idx % NFREQ;
    float re = cs_out[(size_t)m * 202 + f];
    float im = cs_out[(size_t)m * 202 + NFREQ + f];
    magv[idx] = sqrtf(re * re + im * im) * 0.005f;
}

__global__ __launch_bounds__(256) void mag_bf_kernel(
    const float* __restrict__ cs_out, short* __restrict__ magv)
{
    int idx = blockIdx.x * 256 + threadIdx.x;
    if (idx >= NTOK * 128) return;
    int m = idx >> 7, f = idx & 127;
    short out = 0;
    if (f < NFREQ) {
        float re = cs_out[(size_t)m * 202 + f];
        float im = cs_out[(size_t)m * 202 + NFREQ + f];
        out = f2bf(sqrtf(re * re + im * im) * 0.005f);
    }
    magv[idx] = out;
}

// ---------------------------------------------------------------------------
// depthwise 7x7 pos conv + residual. block = (b, 16-d slice, 4-c tile+halo)
__global__ __launch_bounds__(256) void pe_conv3_kernel(
    const float* __restrict__ patch, const float* __restrict__ pw,
    float* __restrict__ hidden)
{
    int b = blockIdx.x, dc = blockIdx.y, ct = blockIdx.z;
    int d0 = dc * 16, c0 = ct * 4;
    __shared__ float pl[10 * 30 * 16];
    __shared__ float wl[49 * 16];
    int tid = threadIdx.x;
    int dd = tid & 15;
    int d = d0 + dd;

    for (int i = tid; i < 10 * 30 * 16; i += 256) {
        int ddl = i & 15, r = i >> 4;
        int l = r % 30, cr = r / 30;
        int cc = c0 + cr - 3, dl = d0 + ddl;
        pl[i] = (cc >= 0 && cc < CH && dl < 200)
                    ? patch[((size_t)(b * CH + cc) * LLEN + l) * 200 + dl] : 0.f;
    }
    for (int i = tid; i < 49 * 16; i += 256) {
        int k = i >> 4, dl = d0 + (i & 15);
        wl[i] = (dl < 200) ? pw[(size_t)dl * 49 + k] : 0.f;
    }
    __syncthreads();

    float wreg[49];
#pragma unroll
    for (int k = 0; k < 49; k++) wreg[k] = wl[k * 16 + dd];

    for (int o = tid; o < 4 * 30 * 16; o += 256) {
        int r2 = o >> 4;
        int l = r2 % 30, ci = r2 / 30;
        int c = c0 + ci;
        if (c >= CH) continue;
        float acc = pl[((ci + 3) * 30 + l) * 16 + dd];
#pragma unroll
        for (int i = 0; i < 7; i++) {
#pragma unroll
            for (int j = 0; j < 7; j++) {
                int ll = l + j - 3;
                if (ll < 0 || ll >= LLEN) continue;
                acc = fmaf(pl[((ci + i) * 30 + ll) * 16 + dd], wreg[i * 7 + j], acc);
            }
        }
        if (d < 200) hidden[((size_t)(b * CH + c) * LLEN + l) * 200 + d] = acc;
    }
}

// ---------------------------------------------------------------------------
__global__ __launch_bounds__(64) void add_rmsnorm_kernel(
    const float* __restrict__ hidden, float* __restrict__ residual,
    const float* __restrict__ wn, float* __restrict__ u,
    short* __restrict__ ubf, int first)
{
    int m = blockIdx.x;
    int lane = threadIdx.x;
    const float* hr = hidden + (size_t)m * 200;
    float* rr = residual + (size_t)m * 200;
    float v[4];
    float ss = 0.f;
#pragma unroll
    for (int i = 0; i < 4; i++) {
        int k = lane + i * 64;
        float xv = 0.f;
        if (k < 200) {
            xv = hr[k] + (first ? 0.f : rr[k]);
            rr[k] = xv;
        }
        v[i] = xv;
        ss = fmaf(xv, xv, ss);
    }
#pragma unroll
    for (int o = 32; o; o >>= 1) ss += __shfl_xor(ss, o, 64);
    float rstd = rsqrtf(ss * (1.f / 200.f) + EPS);
#pragma unroll
    for (int i = 0; i < 4; i++) {
        int k = lane + i * 64;
        float val = v[i] * rstd * ((k < 200) ? wn[k] : 0.f);
        if (k < 200 && u) u[(size_t)m * 200 + k] = val;
        if (ubf) {
            if (k < 200) ubf[(size_t)m * 224 + k] = f2bf(val);
            else if (k < 224) ubf[(size_t)m * 224 + k] = 0;
        }
    }
}

// ---------------------------------------------------------------------------
// Fused: residual += hidden; u = rmsnorm*wn -> ubf; dt GEMV fp32.
__global__ __launch_bounds__(256) void norm_dt_kernel(
    const float* __restrict__ hidden, float* __restrict__ residual,
    const float* __restrict__ wn, short* __restrict__ ubf,
    const float* __restrict__ Win, const float* __restrict__ dt_bias,
    float* __restrict__ dtb, int layer, int first)
{
    int m = blockIdx.x;
    int tid = threadIdx.x;
    __shared__ float su[200];
    __shared__ float rs[4];
    float xv = 0.f;
    if (tid < 200) {
        xv = hidden[(size_t)m * 200 + tid] + (first ? 0.f : residual[(size_t)m * 200 + tid]);
        residual[(size_t)m * 200 + tid] = xv;
    }
    float ss = xv * xv;
#pragma unroll
    for (int o = 32; o; o >>= 1) ss += __shfl_xor(ss, o, 64);
    int lane = tid & 63, w = tid >> 6;
    if (lane == 0) rs[w] = ss;
    __syncthreads();
    float rstd = rsqrtf((rs[0] + rs[1] + rs[2] + rs[3]) * (1.f / 200.f) + EPS);
    if (tid < 200) {
        float val = xv * rstd * wn[tid];
        su[tid] = val;
        ubf[(size_t)m * 224 + tid] = f2bf(val);
    } else if (tid < 224) {
        ubf[(size_t)m * 224 + tid] = 0;
    }
    __syncthreads();
    int h = tid >> 5, l = tid & 31;
    const float* wr = Win + (size_t)layer * D_IN_PROJ * 200 + (size_t)(928 + h) * 200;
    float s = 0.f;
    for (int k = l; k < 200; k += 32) s = fmaf(su[k], wr[k], s);
    s += __shfl_xor(s, 16, 32);
    s += __shfl_xor(s, 8, 32);
    s += __shfl_xor(s, 4, 32);
    s += __shfl_xor(s, 2, 32);
    s += __shfl_xor(s, 1, 32);
    if (l == 0) {
        float raw = s + dt_bias[layer * NHEADS + h];
        dtb[(size_t)m * NHEADS + h] = (raw > 20.f) ? raw : log1pf(expf(raw));
    }
}

// fp32 dt GEMV (fallback)
__global__ __launch_bounds__(256) void dt_gemv_kernel(
    const float* __restrict__ u, const float* __restrict__ Win,
    const float* __restrict__ dt_bias, float* __restrict__ dtb, int layer)
{
    int tid = threadIdx.x;
    int tok = blockIdx.x * 4 + (tid >> 6);
    int head = (tid >> 3) & 7;
    int l8 = tid & 7;
    const float* ur = u + (size_t)tok * 200;
    const float* wr = Win + (size_t)layer * D_IN_PROJ * 200 + (size_t)(928 + head) * 200;
    float s = 0.f;
    for (int k = l8; k < 200; k += 8) s = fmaf(ur[k], wr[k], s);
    s += __shfl_xor(s, 1, 64);
    s += __shfl_xor(s, 2, 64);
    s += __shfl_xor(s, 4, 64);
    if (l8 == 0) {
        float raw = s + dt_bias[layer * NHEADS + head];
        dtb[(size_t)tok * NHEADS + head] = (raw > 20.f) ? raw : log1pf(expf(raw));
    }
}

// ---------------------------------------------------------------------------
// xBC = silu(causal depthwise conv4), t-tiled
__global__ __launch_bounds__(256) void dtconv2_kernel(
    const float* __restrict__ zxbcdt, const float* __restrict__ cw,
    const float* __restrict__ cb, float* __restrict__ xBC, int layer)
{
    int b = blockIdx.x, tt = blockIdx.y;
    int t0 = tt * 8;
    __shared__ float zs[11][528];
    const float* cwl = cw + (size_t)layer * CONV_DIM * 4;
    const float* cbl = cb + (size_t)layer * CONV_DIM;
    for (int i = threadIdx.x; i < 11 * 528; i += 256) {
        int r = i / 528, ch = i - r * 528;
        int t = t0 - 3 + r;
        zs[r][ch] = (t >= 0 && t < SEQ)
                        ? zxbcdt[(size_t)(b * SEQ + t) * D_IN_PROJ + D_INNER + ch] : 0.f;
    }
    __syncthreads();
    for (int o = threadIdx.x; o < 8 * 528; o += 256) {
        int tr = o / 528, ch = o - tr * 528;
        int t = t0 + tr;
        if (t >= SEQ) continue;
        float acc = cbl[ch];
#pragma unroll
        for (int k = 0; k < 4; k++)
            acc = fmaf(zs[tr + k][ch], cwl[ch * 4 + k], acc);
        xBC[(size_t)(b * SEQ + t) * CONV_DIM + ch] = acc / (1.f + __expf(-acc));
    }
}

// ---------------------------------------------------------------------------
// SSD pass 1 as ONE MFMA GEMM per (b,h,chunk) (verified R22).
__global__ __launch_bounds__(256) void ssd_state12_kernel(
    const float* __restrict__ xBC, const float* __restrict__ dtb,
    const float* __restrict__ A_log, float* __restrict__ Sbuf,
    float* __restrict__ Pd, int layer, int lchunk, int nchunk)
{
    int b = blockIdx.x, c = blockIdx.y, bz = blockIdx.z;
    int tid = threadIdx.x;
    int w = tid >> 6, lane = tid & 63;
    int h = bz * 4 + w;
    int t0 = c * lchunk;
    float A = -expf(A_log[layer * NHEADS + h]);

    __shared__ __align__(16) short Bt[64 * 64];      // [n][s], block-shared
    __shared__ __align__(16) short Xw[4][64 * 64];   // [p][s], per wave

    for (int i = tid; i < 512; i += 256) ((s8v*)Bt)[i] = (s8v)0;
#pragma unroll
    for (int ww = 0; ww < 4; ww++)
        for (int i = tid; i < 512; i += 256) ((s8v*)Xw[ww])[i] = (s8v)0;
    __syncthreads();

    float dtv = 0.f;
    if (lane < lchunk) dtv = dtb[(size_t)(b * SEQ + t0 + lane) * NHEADS + h];
    float lc = dtv * A;
#pragma unroll
    for (int o = 1; o < 64; o <<= 1) {
        float v = __shfl_up(lc, o, 64);
        if (lane >= o) lc += v;
    }
    float lcTot = __shfl(lc, lchunk - 1, 64);
    float wdec = __expf(lcTot - lc) * dtv;

    for (int idx = tid; idx < lchunk * 64; idx += 256) {
        int s = idx >> 6, n = idx & 63;
        float v = xBC[(size_t)(b * SEQ + t0 + s) * CONV_DIM + D_INNER + n];
        Bt[n * 64 + s] = f2bf(v);
    }
    for (int idx = lane; idx < lchunk * HEADDIM; idx += 64) {
        int s = idx / HEADDIM, p = idx - s * HEADDIM;
        float ws = __shfl(wdec, s, 64);
        float v = xBC[(size_t)(b * SEQ + t0 + s) * CONV_DIM + h * HEADDIM + p] * ws;
        Xw[w][p * 64 + s] = f2bf(v);
    }
    __syncthreads();

    int lm = lane & 15, lg = lane >> 4;
    f32x4 acc[4][4];
#pragma unroll
    for (int i = 0; i < 4; i++)
#pragma unroll
        for (int j = 0; j < 4; j++) acc[i][j] = (f32x4)0.f;

#pragma unroll
    for (int k0 = 0; k0 < 64; k0 += 32) {
        s8v af[4], bf[4];
#pragma unroll
        for (int i = 0; i < 4; i++)
            af[i] = *(const s8v*)&Xw[w][(i * 16 + lm) * 64 + k0 + lg * 8];
#pragma unroll
        for (int j = 0; j < 4; j++)
            bf[j] = *(const s8v*)&Bt[(j * 16 + lm) * 64 + k0 + lg * 8];
#pragma unroll
        for (int i = 0; i < 4; i++)
#pragma unroll
            for (int j = 0; j < 4; j++)
                acc[i][j] = __builtin_amdgcn_mfma_f32_16x16x32_bf16(
                    af[i], bf[j], acc[i][j], 0, 0, 0);
    }

    float* Sb = Sbuf + ((size_t)((b * NHEADS + h) * nchunk + c)) * (HEADDIM * 64);
#pragma unroll
    for (int i = 0; i < 4; i++) {
        int pbase = i * 16 + lg * 4;
#pragma unroll
        for (int r = 0; r < 4; r++) {
            int p = pbase + r;
            if (p >= HEADDIM) continue;
#pragma unroll
            for (int j = 0; j < 4; j++) {
                int n = j * 16 + lm;
                Sb[(size_t)p * 64 + n] = acc[i][j][r];
            }
        }
    }
    if (lane == 0) Pd[(b * NHEADS + h) * nchunk + c] = __expf(lcTot);
}

// single-step pass 1 (fallback)
__global__ __launch_bounds__(512) void ssd_state_kernel(
    const float* __restrict__ xBC, const float* __restrict__ dtb,
    const float* __restrict__ A_log, float* __restrict__ Sbuf,
    float* __restrict__ Pd, int layer, int lchunk, int nchunk)
{
    int b = blockIdx.x, c = blockIdx.y;
    int tid = threadIdx.x;
    int h = tid >> 6, p = tid & 63;
    float A = -expf(A_log[layer * NHEADS + h]);

    __shared__ float sh[2][544];
    int t0 = c * lchunk, tend = t0 + lchunk;

    {
        const float* base = xBC + (size_t)(b * SEQ + t0) * CONV_DIM;
        sh[0][tid] = base[tid];
        if (tid < 24) {
            int e2 = 512 + tid;
            sh[0][e2] = (e2 < 528) ? base[e2]
                                   : dtb[(size_t)(b * SEQ + t0) * NHEADS + (e2 - 528)];
        }
    }
    __syncthreads();

    float s[64];
#pragma unroll
    for (int n = 0; n < 64; n++) s[n] = 0.f;
    float pacc = 1.f;

    for (int t = t0; t < tend; t++) {
        int cur = (t - t0) & 1, nxt = cur ^ 1;
        float pf0 = 0.f, pf1 = 0.f;
        if (t + 1 < tend) {
            const float* base = xBC + (size_t)(b * SEQ + t + 1) * CONV_DIM;
            pf0 = base[tid];
            if (tid < 24) {
                int e2 = 512 + tid;
                pf1 = (e2 < 528) ? base[e2]
                                 : dtb[(size_t)(b * SEQ + t + 1) * NHEADS + (e2 - 528)];
            }
        }
        float dtv = sh[cur][528 + h];
        float xp  = (p < HEADDIM) ? sh[cur][h * HEADDIM + p] : 0.f;
        float dA = __expf(dtv * A);
        float u  = dtv * xp;
        pacc *= dA;
        const float4* B4 = (const float4*)&sh[cur][D_INNER];
#pragma unroll
        for (int n4 = 0; n4 < 16; n4++) {
            float4 bq = B4[n4];
            s[4 * n4 + 0] = fmaf(s[4 * n4 + 0], dA, u * bq.x);
            s[4 * n4 + 1] = fmaf(s[4 * n4 + 1], dA, u * bq.y);
            s[4 * n4 + 2] = fmaf(s[4 * n4 + 2], dA, u * bq.z);
            s[4 * n4 + 3] = fmaf(s[4 * n4 + 3], dA, u * bq.w);
        }
        if (t + 1 < tend) {
            sh[nxt][tid] = pf0;
            if (tid < 24) sh[nxt][512 + tid] = pf1;
        }
        __syncthreads();
    }

    if (p < HEADDIM) {
        float* Sb = Sbuf + ((size_t)((b * NHEADS + h) * nchunk + c)) * (HEADDIM * 64)
                    + p * 64;
#pragma unroll
        for (int n4 = 0; n4 < 16; n4++)
            ((float4*)Sb)[n4] = make_float4(s[4 * n4], s[4 * n4 + 1],
                                            s[4 * n4 + 2], s[4 * n4 + 3]);
    }
    if (p == 0) Pd[(b * NHEADS + h) * nchunk + c] = pacc;
}

// ---------------------------------------------------------------------------
// Pass 2, parallel over element tiles: grid (128 bh, 13), 256 thr.
__global__ __launch_bounds__(256) void ssd_scan2b_kernel(
    float* __restrict__ Sbuf, const float* __restrict__ Pd, int nchunk)
{
    int bh = blockIdx.x;
    int e = blockIdx.y * 256 + threadIdx.x;
    if (e >= HEADDIM * 64) return;
    float* base = Sbuf + (size_t)bh * nchunk * (HEADDIM * 64) + e;
    const float* pd = Pd + bh * nchunk;
    float cur = 0.f;
    for (int c = 0; c < nchunk; c++) {
        float l = base[(size_t)c * (HEADDIM * 64)];
        base[(size_t)c * (HEADDIM * 64)] = cur;
        cur = fmaf(pd[c], cur, l);
    }
}

// ---------------------------------------------------------------------------
// SSD pass 3, chunked MFMA (R25 = R24 + K-dim pad fix). grid (b, chunk, 2),
// 4 waves = heads. Packed LDS 76.9KB (2 blocks/CU): Ct/Bt block-shared,
// Gm+Xt per wave; Sn from global Sbuf as reg-converted B-fragments.
// Xt cols [lchunk,64) zeroed: they are contracted (K) by Y1 against exact-
// zero G entries, and MFMA 0*NaN = NaN (the R24 bug). Zero writes are
// disjoint from staging writes (cols < lchunk) -> no extra barrier.
__global__ __launch_bounds__(256) void ssd_out13_kernel(
    const float* __restrict__ xBC, const float* __restrict__ dtb,
    const float* __restrict__ zxbcdt, const float* __restrict__ A_log,
    const float* __restrict__ Dv, const float* __restrict__ Sbuf,
    const float* __restrict__ gw, short* __restrict__ ybf,
    float* __restrict__ ssq, int layer, int lchunk, int nchunk)
{
    int b = blockIdx.x, c = blockIdx.y, bz = blockIdx.z;
    int tid = threadIdx.x;
    int w = tid >> 6, lane = tid & 63;
    int h = bz * 4 + w;
    int t0 = c * lchunk;
    float A = -expf(A_log[layer * NHEADS + h]);
    float Dh = Dv[layer * NHEADS + h];

    // packed LDS: Ct[64*72] | Bt[64*72] | Gm[4][48*72] | Xt[4][50*72] | pad
    __shared__ __align__(16) short SH[38448];
    short* Ct = SH;
    short* Bt = SH + 4608;
    short* Gm = SH + 9216 + w * 3456;
    short* Xt = SH + 23040 + w * 3600;

    // dt + inclusive log-decay prefix (per wave/head)
    float dtv = 0.f;
    if (lane < lchunk) dtv = dtb[(size_t)(b * SEQ + t0 + lane) * NHEADS + h];
    float lc = dtv * A;
#pragma unroll
    for (int o = 1; o < 64; o <<= 1) {
        float v = __shfl_up(lc, o, 64);
        if (lane >= o) lc += v;
    }

    // stage Ct/Bt (block-coop, coalesced 128-float rows)
    for (int idx = tid; idx < lchunk * 64; idx += 256) {
        int s = idx >> 6, n = idx & 63;
        const float* row = xBC + (size_t)(b * SEQ + t0 + s) * CONV_DIM + D_INNER;
        Bt[s * 72 + n] = f2bf(row[n]);
        Ct[s * 72 + n] = f2bf(row[64 + n]);
    }
    // stage Xt (block-coop, coalesced 200-float x-slice of this head group)
    for (int idx = tid; idx < lchunk * 200; idx += 256) {
        int s = idx / 200, d = idx - s * 200;
        int hw = d / 50, p = d - hw * 50;
        float v = xBC[(size_t)(b * SEQ + t0 + s) * CONV_DIM + bz * 200 + d];
        (SH + 23040 + hw * 3600)[p * 72 + s] = f2bf(v);
    }
    // zero Xt K-pad cols [lchunk,64): contracted against exact-zero G
    // entries; without this, 0 * garbage-NaN = NaN in valid outputs.
    {
        int kw = 64 - lchunk;                     // 26 for lchunk=38
        for (int idx = tid; idx < 4 * 50 * kw; idx += 256) {
            int per = 50 * kw;
            int hw = idx / per, rem = idx - hw * per;
            int p = rem / kw, s = lchunk + (rem - p * kw);
            (SH + 23040 + hw * 3600)[p * 72 + s] = 0;
        }
    }

    int lm = lane & 15, lg = lane >> 4;

    // preload Sn B-fragments from global (fp32 -> bf16 in regs); rows p>=50
    // read past this chunk's tile into adjacent Sbuf/Pd memory (finite):
    // they feed only masked output cols.
    s8v b2r[2][4];
    {
        const float* Sb = Sbuf + ((size_t)((b * NHEADS + h) * nchunk + c)) * (HEADDIM * 64);
#pragma unroll
        for (int kk = 0; kk < 2; kk++)
#pragma unroll
            for (int j = 0; j < 4; j++) {
                int off = (j * 16 + lm) * 64 + kk * 32 + lg * 8;
                float4 f0 = *(const float4*)&Sb[off];
                float4 f1 = *(const float4*)&Sb[off + 4];
                s8v t;
                t[0] = f2bf(f0.x); t[1] = f2bf(f0.y);
                t[2] = f2bf(f0.z); t[3] = f2bf(f0.w);
                t[4] = f2bf(f1.x); t[5] = f2bf(f1.y);
                t[6] = f2bf(f1.z); t[7] = f2bf(f1.w);
                b2r[kk][j] = t;
            }
    }
    __syncthreads();

    // ---- CB = Ct @ Bt^T (M tiles i<3: t<48) ----
    f32x4 acc[3][4];
#pragma unroll
    for (int i = 0; i < 3; i++)
#pragma unroll
        for (int j = 0; j < 4; j++) acc[i][j] = (f32x4)0.f;
#pragma unroll
    for (int k0 = 0; k0 < 64; k0 += 32) {
        s8v af[3], bfv[4];
#pragma unroll
        for (int i = 0; i < 3; i++)
            af[i] = *(const s8v*)&Ct[(i * 16 + lm) * 72 + k0 + lg * 8];
#pragma unroll
        for (int j = 0; j < 4; j++)
            bfv[j] = *(const s8v*)&Bt[(j * 16 + lm) * 72 + k0 + lg * 8];
#pragma unroll
        for (int i = 0; i < 3; i++)
#pragma unroll
            for (int j = 0; j < 4; j++)
                acc[i][j] = __builtin_amdgcn_mfma_f32_16x16x32_bf16(
                    af[i], bfv[j], acc[i][j], 0, 0, 0);
    }

    // ---- scale + mask -> G (per-wave LDS; same-wave write->read) ----
    // G fully written for t<48, s<64; s>t (incl. all pad s) selects exact 0.
    float lcs4[4], dts4[4];
#pragma unroll
    for (int j = 0; j < 4; j++) {
        int s = j * 16 + lm;
        lcs4[j] = __shfl(lc, s, 64);
        dts4[j] = __shfl(dtv, s, 64);
    }
#pragma unroll
    for (int i = 0; i < 3; i++) {
#pragma unroll
        for (int r = 0; r < 4; r++) {
            int t = i * 16 + lg * 4 + r;
            float lct = __shfl(lc, t, 64);
#pragma unroll
            for (int j = 0; j < 4; j++) {
                int s = j * 16 + lm;
                float gv = (s <= t)
                    ? acc[i][j][r] * __expf(lct - lcs4[j]) * dts4[j] : 0.f;
                Gm[t * 72 + s] = f2bf(gv);
            }
        }
    }

    // ---- Y1 = G @ Xt^T ; Y2 = Ct @ Sn^T (Sn from regs) ----
    f32x4 acc2[3][4];
#pragma unroll
    for (int i = 0; i < 3; i++)
#pragma unroll
        for (int j = 0; j < 4; j++) { acc[i][j] = (f32x4)0.f; acc2[i][j] = (f32x4)0.f; }
#pragma unroll
    for (int k0 = 0; k0 < 64; k0 += 32) {
        int kk = k0 >> 5;
        s8v a1[3], b1[4], a2[3];
#pragma unroll
        for (int i = 0; i < 3; i++) {
            a1[i] = *(const s8v*)&Gm[(i * 16 + lm) * 72 + k0 + lg * 8];
            a2[i] = *(const s8v*)&Ct[(i * 16 + lm) * 72 + k0 + lg * 8];
        }
#pragma unroll
        for (int j = 0; j < 4; j++)
            b1[j] = *(const s8v*)&Xt[(j * 16 + lm) * 72 + k0 + lg * 8];
#pragma unroll
        for (int i = 0; i < 3; i++)
#pragma unroll
            for (int j = 0; j < 4; j++) {
                acc[i][j]  = __builtin_amdgcn_mfma_f32_16x16x32_bf16(
                    a1[i], b1[j], acc[i][j], 0, 0, 0);
                acc2[i][j] = __builtin_amdgcn_mfma_f32_16x16x32_bf16(
                    a2[i], b2r[kk][j], acc2[i][j], 0, 0, 0);
            }
    }

    // ---- epilogue ----
    float gwv[4];
#pragma unroll
    for (int j = 0; j < 4; j++) {
        int p = j * 16 + lm;
        gwv[j] = (p < HEADDIM) ? gw[(size_t)layer * D_INNER + h * HEADDIM + p] : 0.f;
    }
#pragma unroll
    for (int i = 0; i < 3; i++) {
#pragma unroll
        for (int r = 0; r < 4; r++) {
            int t = i * 16 + lg * 4 + r;
            float lct = __shfl(lc, t, 64);
            float elc = __expf(lct);
            int ok = (t < lchunk);
            size_t grow = (size_t)(b * SEQ + t0 + t);
            size_t row0 = grow * 416;
            float gsum = 0.f;
#pragma unroll
            for (int j = 0; j < 4; j++) {
                int p = j * 16 + lm;
                float yv = acc[i][j][r] + elc * acc2[i][j][r];
                float g = 0.f;
                if (p < HEADDIM && ok) {
                    float xv = xBC[grow * CONV_DIM + h * HEADDIM + p];
                    float zv = zxbcdt[grow * D_IN_PROJ + h * HEADDIM + p];
                    yv += Dh * xv;
                    g = yv * (zv / (1.f + __expf(-zv)));
                    ybf[row0 + h * HEADDIM + p] = f2bf(g * gwv[j]);
                }
                gsum += g * g;
            }
            gsum += __shfl_xor(gsum, 1, 64);
            gsum += __shfl_xor(gsum, 2, 64);
            gsum += __shfl_xor(gsum, 4, 64);
            gsum += __shfl_xor(gsum, 8, 64);
            if (lm == 0 && ok) ssq[grow * NHEADS + h] = gsum;
            if (bz == 0 && w == 0 && ok) ybf[row0 + 400 + lm] = 0;
        }
    }
}

// combine per-head sums -> per-token rstd for the GEMM row-scale
__global__ __launch_bounds__(256) void rstd_kernel(
    const float* __restrict__ ssq, float* __restrict__ rstdb)
{
    int m = blockIdx.x * 256 + threadIdx.x;
    if (m >= NTOK) return;
    const float4* q = (const float4*)(ssq + (size_t)m * NHEADS);
    float4 a = q[0], bq = q[1];
    float tot = ((a.x + a.y) + (a.z + a.w)) + ((bq.x + bq.y) + (bq.z + bq.w));
    rstdb[m] = rsqrtf(tot * (1.f / D_INNER) + EPS);
}

// Pass 3 (fallback, fp32 y out, single-step)
__global__ __launch_bounds__(512) void ssd_out_kernel(
    const float* __restrict__ xBC, const float* __restrict__ dtb,
    const float* __restrict__ A_log, const float* __restrict__ Dv,
    const float* __restrict__ Sbuf, float* __restrict__ y,
    int layer, int lchunk, int nchunk)
{
    int b = blockIdx.x, c = blockIdx.y;
    int tid = threadIdx.x;
    int h = tid >> 6, p = tid & 63;
    float A = -expf(A_log[layer * NHEADS + h]);
    float Dh = Dv[layer * NHEADS + h];

    __shared__ float sh[2][544];
    int t0 = c * lchunk, tend = t0 + lchunk;

    {
        const float* base = xBC + (size_t)(b * SEQ + t0) * CONV_DIM;
        sh[0][tid] = base[tid];
        if (tid < 24) {
            int e2 = 512 + tid;
            sh[0][e2] = (e2 < 528) ? base[e2]
                                   : dtb[(size_t)(b * SEQ + t0) * NHEADS + (e2 - 528)];
        }
    }

    float s[64];
    if (p < HEADDIM) {
        const float* Sb = Sbuf + ((size_t)((b * NHEADS + h) * nchunk + c)) * (HEADDIM * 64)
                          + p * 64;
#pragma unroll
        for (int n4 = 0; n4 < 16; n4++) {
            float4 v = ((const float4*)Sb)[n4];
            s[4 * n4] = v.x; s[4 * n4 + 1] = v.y; s[4 * n4 + 2] = v.z; s[4 * n4 + 3] = v.w;
        }
    } else {
#pragma unroll
        for (int n = 0; n < 64; n++) s[n] = 0.f;
    }
    __syncthreads();

    for (int t = t0; t < tend; t++) {
        int cur = (t - t0) & 1, nxt = cur ^ 1;
        float pf0 = 0.f, pf1 = 0.f;
        if (t + 1 < tend) {
            const float* base = xBC + (size_t)(b * SEQ + t + 1) * CONV_DIM;
            pf0 = base[tid];
            if (tid < 24) {
                int e2 = 512 + tid;
                pf1 = (e2 < 528) ? base[e2]
                                 : dtb[(size_t)(b * SEQ + t + 1) * NHEADS + (e2 - 528)];
            }
        }
        float dtv = sh[cur][528 + h];
        float xp  = (p < HEADDIM) ? sh[cur][h * HEADDIM + p] : 0.f;
        float dA = __expf(dtv * A);
        float u  = dtv * xp;
        const float4* B4 = (const float4*)&sh[cur][D_INNER];
        const float4* C4 = (const float4*)&sh[cur][D_INNER + D_STATE];
        float y0 = 0.f, y1 = 0.f, y2 = 0.f, y3 = 0.f;
#pragma unroll
        for (int n4 = 0; n4 < 16; n4++) {
            float4 bq = B4[n4];
            float4 cq = C4[n4];
            float t0v = fmaf(s[4 * n4 + 0], dA, u * bq.x);
            float t1v = fmaf(s[4 * n4 + 1], dA, u * bq.y);
            float t2v = fmaf(s[4 * n4 + 2], dA, u * bq.z);
            float t3v = fmaf(s[4 * n4 + 3], dA, u * bq.w);
            s[4 * n4 + 0] = t0v; s[4 * n4 + 1] = t1v;
            s[4 * n4 + 2] = t2v; s[4 * n4 + 3] = t3v;
            y0 = fmaf(t0v, cq.x, y0);
            y1 = fmaf(t1v, cq.y, y1);
            y2 = fmaf(t2v, cq.z, y2);
            y3 = fmaf(t3v, cq.w, y3);
        }
        if (p < HEADDIM) {
            float yv = (y0 + y1) + (y2 + y3);
            y[(size_t)(b * SEQ + t) * D_INNER + h * HEADDIM + p] = fmaf(xp, Dh, yv);
        }
        if (t + 1 < tend) {
            sh[nxt][tid] = pf0;
            if (tid < 24) sh[nxt][512 + tid] = pf1;
        }
        __syncthreads();
    }
}

// ---------------------------------------------------------------------------
// fallback gate+norm
__global__ __launch_bounds__(256) void gate_norm_kernel(
    float* __restrict__ y, const float* __restrict__ zxbcdt,
    const float* __restrict__ gw, short* __restrict__ ybf, int layer)
{
    int m = blockIdx.x;
    __shared__ float buf[D_INNER];
    __shared__ float red[4];
    const float* z = zxbcdt + (size_t)m * D_IN_PROJ;
    float* yr = y + (size_t)m * D_INNER;
    const float* gwl = gw + (size_t)layer * D_INNER;
    float ss = 0.f;
    for (int k = threadIdx.x; k < D_INNER; k += 256) {
        float zv = z[k];
        float sz = zv / (1.f + expf(-zv));
        float g = yr[k] * sz;
        buf[k] = g;
        ss = fmaf(g, g, ss);
    }
    int lane = threadIdx.x & 63, w = threadIdx.x >> 6;
#pragma unroll
    for (int o = 32; o; o >>= 1) ss += __shfl_xor(ss, o, 64);
    if (lane == 0) red[w] = ss;
    __syncthreads();
    float tot = red[0] + red[1] + red[2] + red[3];
    float rstd = rsqrtf(tot * (1.f / D_INNER) + EPS);
    for (int k = threadIdx.x; k < 416; k += 256) {
        if (k < D_INNER) {
            float v = buf[k] * rstd * gwl[k];
            yr[k] = v;
            if (ybf) ybf[(size_t)m * 416 + k] = f2bf(v);
        } else if (ybf) {
            ybf[(size_t)m * 416 + k] = 0;
        }
    }
}

// ---------------------------------------------------------------------------
extern "C" void kernel_launch(void* const* d_in, const int* in_sizes, int n_in,
                              void* d_out, int out_size, void* d_ws, size_t ws_size,
                              hipStream_t stream)
{
    const float* x         = (const float*)d_in[0];
    const float* pe_conv_w = (const float*)d_in[1];
    const float* proj_in_w = (const float*)d_in[2];
    const float* gn_g      = (const float*)d_in[3];
    const float* gn_b      = (const float*)d_in[4];
    const float* spec_w    = (const float*)d_in[5];
    const float* norm_w    = (const float*)d_in[6];
    const float* in_proj_w = (const float*)d_in[7];
    const float* conv_w    = (const float*)d_in[8];
    const float* conv_b    = (const float*)d_in[9];
    const float* dt_bias   = (const float*)d_in[10];
    const float* A_log     = (const float*)d_in[11];
    const float* Dv        = (const float*)d_in[12];
    const float* gnorm_w   = (const float*)d_in[13];
    const float* out_proj_w= (const float*)d_in[14];
    const float* norm_f_w  = (const float*)d_in[15];
    const float* head_w    = (const float*)d_in[16];
    const float* head_b    = (const float*)d_in[17];
    float* out = (float*)d_out;
    float* ws  = (float*)d_ws;

    // fast gate: 28,011,424 floats = 112.05 MB (prior rounds ran fast at
    // gates up to 136.4 MB on this harness).
    const size_t needA = 28011424ull * sizeof(float);
    int fast = (ws_size >= needA) ? 1 : 0;

    int nchunk, lchunk;
    float *residual = ws, *hidden = ws + 1824000;
    float *zxbcdt, *xBC, *dtb, *Sbuf, *Pd;
    float *ubuf = nullptr, *ybuf = nullptr, *ssq = nullptr, *rstdb = nullptr;
    short *w_in_bf = nullptr, *w_out_bf = nullptr, *w_head_bf = nullptr,
          *w_spec_bf = nullptr, *csmat_bf = nullptr, *x_bf = nullptr,
          *ubuf_bf = nullptr, *ybuf_bf = nullptr, *magb_bf = nullptr;

    if (fast) {
        nchunk = 15; lchunk = 38;               // 15*38 = 570
        zxbcdt = ws + 3648000;                  // 8,536,320
        xBC    = ws + 12184320;                 // 4,815,360
        dtb    = ws + 16999680;                 // 72,960
        Sbuf   = ws + 17072640;                 // 15*128*3200 = 6,144,000
        Pd     = ws + 23216640;                 // 1,920
        short* pool = (short*)(ws + 23218560);
        w_in_bf   = pool;                       // 2,515,968
        w_out_bf  = pool + 2515968;             //   998,400
        w_head_bf = pool + 3514368;             //    44,800
        w_spec_bf = pool + 3559168;             //    25,600
        ubuf_bf   = pool + 3584768;             // 2,042,880
        ybuf_bf   = pool + 5627648;             // 3,793,920 -> 9,421,568 shorts
        ssq       = ws + 27929344;              // 72,960 (NTOK*8)
        rstdb     = ws + 28002304;              // 9,120 -> end 28,011,424
        // preamble-only temporaries in the (then-dead) Sbuf region
        csmat_bf  = (short*)(Sbuf + 4000000);   //    45,248 shorts
        x_bf      = (short*)(Sbuf + 4100000);   // 2,042,880 shorts
        magb_bf   = (short*)(Sbuf + 5200000);   // 1,167,360 shorts (fits 6.14M)
    } else {
        nchunk = 6; lchunk = 95;
        ubuf   = ws + 3648000;
        zxbcdt = ws + 5472000;
        xBC    = ws + 14008320;
        dtb    = ws + 18823680;
        ybuf   = ws + 18896640;
        Sbuf   = ws + 1824000;
        Pd     = ws + 5470000;
    }

    // preamble aliases (dead layer buffers / dead Sbuf)
    float* traw  = fast ? Sbuf : ybuf;
    float* patch = zxbcdt;
    float* csout = fast ? (Sbuf + 2000000) : (xBC + 50000);
    float* csmat = xBC;                         // fallback fp32 DFT matrix
    float* magb  = fast ? nullptr : (xBC + 2000000);
    float* stats = dtb;

    // ---- weight / input casts (fast) ----
    if (fast) {
        cast_pad_kernel<<<(12 * 936 * 224 + 255) / 256, 256, 0, stream>>>(
            in_proj_w, w_in_bf, 12 * 936, 200, 224);
        cast_pad_kernel<<<(12 * 200 * 416 + 255) / 256, 256, 0, stream>>>(
            out_proj_w, w_out_bf, 12 * 200, 400, 416);
        cast_pad_kernel<<<(200 * 224 + 255) / 256, 256, 0, stream>>>(
            head_w, w_head_bf, 200, 200, 224);
        cast_pad_kernel<<<(200 * 128 + 255) / 256, 256, 0, stream>>>(
            spec_w, w_spec_bf, 200, 101, 128);
        cast_pad_kernel<<<(9120 * 224 + 255) / 256, 256, 0, stream>>>(
            x, x_bf, 9120, 200, 224);
        dft_init_bf_kernel<<<(202 * 224 + 255) / 256, 256, 0, stream>>>(csmat_bf);
    } else {
        dft_init_kernel<<<(202 * 200 + 255) / 256, 256, 0, stream>>>(csmat);
    }

    // ---- patch embed ----
    time_conv_kernel<<<NTOK, 256, 0, stream>>>(x, proj_in_w, traw);
    gn_stats_kernel<<<80, 256, 0, stream>>>(traw, stats);
    gn_gelu_kernel<<<(NTOK * 200 + 255) / 256, 256, 0, stream>>>(traw, stats, gn_g, gn_b, patch);
    if (fast) {
        gemm_bf16<<<dim3(2, 72), 256, 0, stream>>>(x_bf, csmat_bf, nullptr, nullptr, csout,
                                                   NTOK, 202, 224, 0);
        mag_bf_kernel<<<(NTOK * 128 + 255) / 256, 256, 0, stream>>>(csout, magb_bf);
        gemm_bf16<<<dim3(2, 72), 256, 0, stream>>>(magb_bf, w_spec_bf, nullptr, nullptr, patch,
                                                   NTOK, 200, 128, 1);
    } else {
        gemm_nt<<<dim3(2, 72), 256, 0, stream>>>(x, csmat, nullptr, csout, NTOK, 202, 200, 0);
        mag_kernel<<<(NTOK * NFREQ + 255) / 256, 256, 0, stream>>>(csout, magb);
        gemm_nt<<<dim3(2, 72), 256, 0, stream>>>(magb, spec_w, nullptr, patch,
                                                 NTOK, 200, NFREQ, 1);
    }
    pe_conv3_kernel<<<dim3(16, 13, 5), 256, 0, stream>>>(patch, pe_conv_w, hidden);

    // ---- layers ----
    for (int i = 0; i < N_LAYER; i++) {
        if (fast) {
            norm_dt_kernel<<<NTOK, 256, 0, stream>>>(hidden, residual, norm_w + i * 200,
                                                     ubuf_bf, in_proj_w, dt_bias, dtb,
                                                     i, (i == 0) ? 1 : 0);
            gemm_bf16<<<dim3(8, 72), 256, 0, stream>>>(
                ubuf_bf, w_in_bf + (size_t)i * 936 * 224, nullptr, nullptr, zxbcdt,
                NTOK, D_IN_PROJ, 224, 0);
        } else {
            add_rmsnorm_kernel<<<NTOK, 64, 0, stream>>>(hidden, residual, norm_w + i * 200,
                                                        ubuf, nullptr, (i == 0) ? 1 : 0);
            dt_gemv_kernel<<<NTOK / 4, 256, 0, stream>>>(ubuf, in_proj_w, dt_bias, dtb, i);
            gemm_nt<<<dim3(8, 72), 256, 0, stream>>>(
                ubuf, in_proj_w + (size_t)i * D_IN_PROJ * 200, nullptr, zxbcdt,
                NTOK, D_IN_PROJ, 200, 0);
        }
        dtconv2_kernel<<<dim3(16, 72), 256, 0, stream>>>(zxbcdt, conv_w, conv_b, xBC, i);
        {
            dim3 g(BATCH, nchunk);
            if (fast) {
                ssd_state12_kernel<<<dim3(BATCH, nchunk, 2), 256, 0, stream>>>(
                    xBC, dtb, A_log, Sbuf, Pd, i, lchunk, nchunk);
                ssd_scan2b_kernel<<<dim3(BATCH * NHEADS, 13), 256, 0, stream>>>(Sbuf, Pd, nchunk);
                ssd_out13_kernel<<<dim3(BATCH, nchunk, 2), 256, 0, stream>>>(
                    xBC, dtb, zxbcdt, A_log, Dv, Sbuf, gnorm_w, ybuf_bf, ssq,
                    i, lchunk, nchunk);
                rstd_kernel<<<(NTOK + 255) / 256, 256, 0, stream>>>(ssq, rstdb);
                gemm_bf16<<<dim3(2, 72), 256, 0, stream>>>(
                    ybuf_bf, w_out_bf + (size_t)i * 200 * 416, nullptr, rstdb, hidden,
                    NTOK, 200, 416, 0);
            } else {
                ssd_state_kernel<<<g, 512, 0, stream>>>(xBC, dtb, A_log, Sbuf, Pd,
                                                        i, lchunk, nchunk);
                ssd_scan2b_kernel<<<dim3(BATCH * NHEADS, 13), 256, 0, stream>>>(Sbuf, Pd, nchunk);
                ssd_out_kernel<<<g, 512, 0, stream>>>(xBC, dtb, A_log, Dv, Sbuf, ybuf,
                                                      i, lchunk, nchunk);
                gate_norm_kernel<<<NTOK, 256, 0, stream>>>(ybuf, zxbcdt, gnorm_w, nullptr, i);
                gemm_nt<<<dim3(2, 72), 256, 0, stream>>>(
                    ybuf, out_proj_w + (size_t)i * 200 * D_INNER, nullptr, hidden,
                    NTOK, 200, D_INNER, 0);
            }
        }
    }

    // ---- final norm + head ----
    add_rmsnorm_kernel<<<NTOK, 64, 0, stream>>>(hidden, residual, norm_f_w,
                                                fast ? nullptr : ubuf,
                                                fast ? ubuf_bf : nullptr, 0);
    if (fast) {
        gemm_bf16<<<dim3(2, 72), 256, 0, stream>>>(ubuf_bf, w_head_bf, head_b, nullptr, out,
                                                   NTOK, 200, 224, 0);
    } else {
        gemm_nt<<<dim3(2, 72), 256, 0, stream>>>(ubuf, head_w, head_b, out,
                                                 NTOK, 200, 200, 0);
    }
}